// Round 2
// baseline (805.620 us; speedup 1.0000x reference)
//
#include <hip/hip_runtime.h>

typedef __attribute__((ext_vector_type(4))) float f32x4;
typedef __attribute__((ext_vector_type(8))) short bf16x8;
typedef __attribute__((ext_vector_type(4))) short s16x4;

__device__ __forceinline__ short f2bf(float f) {
  union { float f; unsigned u; } x; x.f = f;
  return (short)((x.u + 0x7fffu + ((x.u >> 16) & 1u)) >> 16);   // RNE
}

__device__ __forceinline__ bf16x8 pack8(float4 a, float4 b) {
  bf16x8 v;
  v[0] = f2bf(a.x); v[1] = f2bf(a.y); v[2] = f2bf(a.z); v[3] = f2bf(a.w);
  v[4] = f2bf(b.x); v[5] = f2bf(b.y); v[6] = f2bf(b.z); v[7] = f2bf(b.w);
  return v;
}

// ---------------- prep: weights->bf16, q padded->bf16, bias [8][64][64] -----
__global__ __launch_bounds__(256) void prep_kernel(
    const float* __restrict__ qkv_w, const float* __restrict__ proj_w,
    const float* __restrict__ qg, const float* __restrict__ table,
    short* __restrict__ wq_b, short* __restrict__ wp_b,
    short* __restrict__ q_b, float* __restrict__ biasg)
{
  int idx = blockIdx.x * 256 + threadIdx.x;
  if (idx < 131072) { wq_b[idx] = f2bf(qkv_w[idx]); return; }
  idx -= 131072;
  if (idx < 65536) { wp_b[idx] = f2bf(proj_w[idx]); return; }
  idx -= 65536;
  if (idx < 1048576) {                       // q padded: [64 win][8 h][64 n][32 d]
    int d = idx & 31, n = (idx >> 5) & 63, hh = (idx >> 11) & 7, w = idx >> 14;
    float v = (n < 49) ? qg[((w * 8 + hh) * 49 + n) * 32 + d] : 0.f;
    q_b[idx] = f2bf(v);
    return;
  }
  idx -= 1048576;
  if (idx < 32768) {                         // bias padded: [8 h][64 q][64 k]
    int hh = idx >> 12, rem = idx & 4095;
    int q = rem >> 6, k = rem & 63;
    float v = 0.f;
    if (q < 49 && k < 49) {
      int di = q / 7 - k / 7 + 6, dj = q % 7 - k % 7 + 6;
      v = table[(di * 13 + dj) * 8 + hh];
    }
    biasg[idx] = v;
  }
}

// ---------------- fused per-window kernel -----------------------------------
// block = 1 window, 512 threads = 8 waves, wave w == head w. LDS = 80 KiB ->
// 2 blocks/CU.  All D-layout-unfriendly epilogues use operand-swapped MFMA.
__global__ __launch_bounds__(512, 4) void fused_win(
    const float* __restrict__ x, const short* __restrict__ q_b,
    const short* __restrict__ wq_b, const short* __restrict__ wp_b,
    const float* __restrict__ qkv_b, const float* __restrict__ proj_b,
    const float* __restrict__ biasg, float* __restrict__ out)
{
  __shared__ __align__(16) char smem[81920];          // 80 KiB
  short* As = (short*)smem;                           // [64][128] x half-tile
  short* Kl = (short*)(smem + 16384);                 // [64 key][256 c] K
  short* vT = (short*)(smem + 49152);                 // [256 d][64 key] V^T
  short* Ol = (short*)(smem + 49152);                 // [64 q][256 c] (alias vT)

  const int tid = threadIdx.x;
  const int b   = blockIdx.x;
  const int lane = tid & 63;
  const int w   = tid >> 6;
  const int lr  = lane & 15;
  const int lg  = lane >> 4;
  short* Pw = (short*)(smem + 16384 + w * 4096);      // per-wave [64 q][32 k] (alias Kl)

  const float* xsrc = x + (long)b * 49 * 256;

  // -- phase 0: stage x half0 -> As; issue half1 loads (latency hides) ------
  float4 h1[2][2];
  int row0[2], s0[2];
  #pragma unroll
  for (int it = 0; it < 2; ++it) {
    int idx = it * 512 + tid;
    int row = idx >> 4, s = idx & 15;
    row0[it] = row; s0[it] = s;
    bf16x8 v = {};
    if (row < 49) {
      const float4* p = (const float4*)(xsrc + row * 256 + s * 8);
      v = pack8(p[0], p[1]);
    }
    *(bf16x8*)(&As[row * 128 + ((s ^ (row & 7)) << 3)]) = v;
  }
  #pragma unroll
  for (int it = 0; it < 2; ++it) {
    int row = row0[it], s = s0[it];
    if (row < 49) {
      const float4* p = (const float4*)(xsrc + row * 256 + 128 + s * 8);
      h1[it][0] = p[0]; h1[it][1] = p[1];
    } else {
      h1[it][0] = make_float4(0, 0, 0, 0); h1[it][1] = make_float4(0, 0, 0, 0);
    }
  }
  __syncthreads();                                    // B1

  // -- phase 1: kv = x @ qkv_w^T, K-split in halves --------------------------
  // waves 0-3: swapped -> acc[mt][nt] holds kv^T (rows=c, cols=key)
  // waves 4-7: normal  -> acc[mt][nt] holds kv   (rows=key, cols=c)
  f32x4 acc[4][4] = {};
  const short* wbase = wq_b + w * 64 * 256;
  #pragma unroll
  for (int kk = 0; kk < 4; ++kk) {
    bf16x8 xa[4], wf[4];
    #pragma unroll
    for (int t = 0; t < 4; ++t)
      xa[t] = *(const bf16x8*)(&As[(t * 16 + lr) * 128 + (((kk * 4 + lg) ^ (lr & 7)) << 3)]);
    #pragma unroll
    for (int t = 0; t < 4; ++t)
      wf[t] = *(const bf16x8*)(wbase + (t * 16 + lr) * 256 + kk * 32 + lg * 8);
    __builtin_amdgcn_s_setprio(1);
    if (w < 4) {
      #pragma unroll
      for (int mt = 0; mt < 4; ++mt)
        #pragma unroll
        for (int nt = 0; nt < 4; ++nt)
          acc[mt][nt] = __builtin_amdgcn_mfma_f32_16x16x32_bf16(wf[mt], xa[nt], acc[mt][nt], 0, 0, 0);
    } else {
      #pragma unroll
      for (int mt = 0; mt < 4; ++mt)
        #pragma unroll
        for (int nt = 0; nt < 4; ++nt)
          acc[mt][nt] = __builtin_amdgcn_mfma_f32_16x16x32_bf16(xa[mt], wf[nt], acc[mt][nt], 0, 0, 0);
    }
    __builtin_amdgcn_s_setprio(0);
  }
  __syncthreads();                                    // B2 (As reads done)
  #pragma unroll
  for (int it = 0; it < 2; ++it) {
    int row = row0[it], s = s0[it];
    *(bf16x8*)(&As[row * 128 + ((s ^ (row & 7)) << 3)]) = pack8(h1[it][0], h1[it][1]);
  }
  __syncthreads();                                    // B3
  #pragma unroll
  for (int kk = 0; kk < 4; ++kk) {
    bf16x8 xa[4], wf[4];
    #pragma unroll
    for (int t = 0; t < 4; ++t)
      xa[t] = *(const bf16x8*)(&As[(t * 16 + lr) * 128 + (((kk * 4 + lg) ^ (lr & 7)) << 3)]);
    #pragma unroll
    for (int t = 0; t < 4; ++t)
      wf[t] = *(const bf16x8*)(wbase + (t * 16 + lr) * 256 + 128 + kk * 32 + lg * 8);
    __builtin_amdgcn_s_setprio(1);
    if (w < 4) {
      #pragma unroll
      for (int mt = 0; mt < 4; ++mt)
        #pragma unroll
        for (int nt = 0; nt < 4; ++nt)
          acc[mt][nt] = __builtin_amdgcn_mfma_f32_16x16x32_bf16(wf[mt], xa[nt], acc[mt][nt], 0, 0, 0);
    } else {
      #pragma unroll
      for (int mt = 0; mt < 4; ++mt)
        #pragma unroll
        for (int nt = 0; nt < 4; ++nt)
          acc[mt][nt] = __builtin_amdgcn_mfma_f32_16x16x32_bf16(xa[mt], wf[nt], acc[mt][nt], 0, 0, 0);
    }
    __builtin_amdgcn_s_setprio(0);
  }

  // epilogue: +qkv_b, vectorized b64 LDS writes
  if (w < 4) {       // K: lane holds c = w*64+mt*16+lg*4+r, key = nt*16+lr
    #pragma unroll
    for (int mt = 0; mt < 4; ++mt) {
      int c0 = w * 64 + mt * 16 + lg * 4;
      float4 bv = *(const float4*)(qkv_b + c0);
      #pragma unroll
      for (int nt = 0; nt < 4; ++nt) {
        int key = nt * 16 + lr;
        s16x4 sv;
        sv[0] = f2bf(acc[mt][nt][0] + bv.x);
        sv[1] = f2bf(acc[mt][nt][1] + bv.y);
        sv[2] = f2bf(acc[mt][nt][2] + bv.z);
        sv[3] = f2bf(acc[mt][nt][3] + bv.w);
        *(s16x4*)(&Kl[key * 256 + ((((c0 >> 3) ^ (key & 7)) << 3)) + (c0 & 7)]) = sv;
      }
    }
  } else {           // V: lane holds key = mt*16+lg*4+r, d = (w-4)*64+nt*16+lr
    #pragma unroll
    for (int nt = 0; nt < 4; ++nt) {
      int d = (w - 4) * 64 + nt * 16 + lr;
      float bv = qkv_b[256 + d];
      #pragma unroll
      for (int mt = 0; mt < 4; ++mt) {
        int key0 = mt * 16 + lg * 4;
        s16x4 sv;
        sv[0] = f2bf(acc[mt][nt][0] + bv);
        sv[1] = f2bf(acc[mt][nt][1] + bv);
        sv[2] = f2bf(acc[mt][nt][2] + bv);
        sv[3] = f2bf(acc[mt][nt][3] + bv);
        *(s16x4*)(&vT[d * 64 + ((((key0 >> 3) ^ (d & 7)) << 3)) + (key0 & 7)]) = sv;
      }
    }
  }
  __syncthreads();                                    // B4

  // -- phase 2: S^T = mfma(K, Q): st[kt][qt] lane holds S[q=qt*16+lr][key=kt*16+lg*4+r]
  f32x4 st[4][4] = {};
  {
    const short* qsrc = q_b + ((long)(b >> 6) * 8 + w) * 2048;
    bf16x8 qa[4], kb[4];
    #pragma unroll
    for (int qt = 0; qt < 4; ++qt)
      qa[qt] = *(const bf16x8*)(qsrc + (qt * 16 + lr) * 32 + lg * 8);
    #pragma unroll
    for (int kt = 0; kt < 4; ++kt) {
      int key = kt * 16 + lr;
      kb[kt] = *(const bf16x8*)(&Kl[key * 256 + (((w * 4 + lg) ^ (key & 7)) << 3)]);
    }
    __builtin_amdgcn_s_setprio(1);
    #pragma unroll
    for (int kt = 0; kt < 4; ++kt)
      #pragma unroll
      for (int qt = 0; qt < 4; ++qt)
        st[kt][qt] = __builtin_amdgcn_mfma_f32_16x16x32_bf16(kb[kt], qa[qt], st[kt][qt], 0, 0, 0);
    __builtin_amdgcn_s_setprio(0);
  }
  __syncthreads();                                    // B5 (Kl dead -> P region)

  // -- phase 3: softmax rows are lane-local-ish (2 shfls per reduce) --------
  {
    const float* bh = biasg + w * 4096;
    const float sc = 0.17677669529663687f;            // 32^-0.5
    #pragma unroll
    for (int qt = 0; qt < 4; ++qt) {
      int q = qt * 16 + lr;
      float mx = -1e30f;
      #pragma unroll
      for (int kt = 0; kt < 4; ++kt) {
        int key0 = kt * 16 + lg * 4;
        float4 bv = *(const float4*)(bh + q * 64 + key0);
        #pragma unroll
        for (int r = 0; r < 4; ++r) {
          float t = st[kt][qt][r] * sc + ((r == 0) ? bv.x : (r == 1) ? bv.y : (r == 2) ? bv.z : bv.w);
          if (key0 + r >= 49) t = -1e30f;
          st[kt][qt][r] = t;
          mx = fmaxf(mx, t);
        }
      }
      mx = fmaxf(mx, __shfl_xor(mx, 16));
      mx = fmaxf(mx, __shfl_xor(mx, 32));
      float sum = 0.f;
      #pragma unroll
      for (int kt = 0; kt < 4; ++kt)
        #pragma unroll
        for (int r = 0; r < 4; ++r) {
          float e = __expf(st[kt][qt][r] - mx);
          st[kt][qt][r] = e; sum += e;
        }
      sum += __shfl_xor(sum, 16);
      sum += __shfl_xor(sum, 32);
      float rinv = 1.f / sum;                         // fold 1/sum into P
      #pragma unroll
      for (int kt = 0; kt < 4; ++kt)
        #pragma unroll
        for (int r = 0; r < 4; ++r) st[kt][qt][r] *= rinv;
    }
  }

  // -- phase 4: O^T = mfma(V^T, P^T), P chunked through per-wave LDS --------
  f32x4 o[2][4] = {};                                 // o[dt][qt]
  #pragma unroll
  for (int ks = 0; ks < 2; ++ks) {
    #pragma unroll
    for (int kh = 0; kh < 2; ++kh) {                  // write chunk keys [32ks,32ks+32)
      int kt = ks * 2 + kh;
      int kloc0 = kh * 16 + lg * 4;
      #pragma unroll
      for (int qt = 0; qt < 4; ++qt) {
        int q = qt * 16 + lr;
        s16x4 sv;
        sv[0] = f2bf(st[kt][qt][0]);
        sv[1] = f2bf(st[kt][qt][1]);
        sv[2] = f2bf(st[kt][qt][2]);
        sv[3] = f2bf(st[kt][qt][3]);
        *(s16x4*)(&Pw[q * 32 + ((((kloc0 >> 3) ^ ((q >> 1) & 3)) << 3)) + (kloc0 & 7)]) = sv;
      }
    }
    bf16x8 pa[4], vb[2];
    #pragma unroll
    for (int qt = 0; qt < 4; ++qt) {
      int q = qt * 16 + lr;
      pa[qt] = *(const bf16x8*)(&Pw[q * 32 + ((lg ^ ((q >> 1) & 3)) << 3)]);
    }
    #pragma unroll
    for (int dt = 0; dt < 2; ++dt) {
      int d = w * 32 + dt * 16 + lr;
      vb[dt] = *(const bf16x8*)(&vT[d * 64 + (((ks * 4 + lg) ^ (d & 7)) << 3)]);
    }
    __builtin_amdgcn_s_setprio(1);
    #pragma unroll
    for (int dt = 0; dt < 2; ++dt)
      #pragma unroll
      for (int qt = 0; qt < 4; ++qt)
        o[dt][qt] = __builtin_amdgcn_mfma_f32_16x16x32_bf16(vb[dt], pa[qt], o[dt][qt], 0, 0, 0);
    __builtin_amdgcn_s_setprio(0);
  }
  __syncthreads();                                    // B6 (vT dead)

  // -- phase 5: O^T -> Ol[q][c] with b64 writes -----------------------------
  #pragma unroll
  for (int dt = 0; dt < 2; ++dt) {
    int c0 = w * 32 + dt * 16 + lg * 4;
    #pragma unroll
    for (int qt = 0; qt < 4; ++qt) {
      int q = qt * 16 + lr;
      s16x4 sv;
      sv[0] = f2bf(o[dt][qt][0]);
      sv[1] = f2bf(o[dt][qt][1]);
      sv[2] = f2bf(o[dt][qt][2]);
      sv[3] = f2bf(o[dt][qt][3]);
      *(s16x4*)(&Ol[q * 256 + ((((c0 >> 3) ^ (q & 7)) << 3)) + (c0 & 7)]) = sv;
    }
  }
  __syncthreads();                                    // B7

  // -- phase 6: out = O @ proj_w^T + proj_b (swapped -> float4 stores) ------
  f32x4 po[2][4] = {};                                // po[mt][qt]: rows=out-col, cols=q
  const short* wpb = wp_b + w * 32 * 256;
  #pragma unroll
  for (int kk = 0; kk < 8; ++kk) {
    bf16x8 of[4], wf2[2];
    #pragma unroll
    for (int qt = 0; qt < 4; ++qt)
      of[qt] = *(const bf16x8*)(&Ol[(qt * 16 + lr) * 256 + (((kk * 4 + lg) ^ (lr & 7)) << 3)]);
    #pragma unroll
    for (int mt = 0; mt < 2; ++mt)
      wf2[mt] = *(const bf16x8*)(wpb + (mt * 16 + lr) * 256 + kk * 32 + lg * 8);
    __builtin_amdgcn_s_setprio(1);
    #pragma unroll
    for (int mt = 0; mt < 2; ++mt)
      #pragma unroll
      for (int qt = 0; qt < 4; ++qt)
        po[mt][qt] = __builtin_amdgcn_mfma_f32_16x16x32_bf16(wf2[mt], of[qt], po[mt][qt], 0, 0, 0);
    __builtin_amdgcn_s_setprio(0);
  }
  float* od = out + (long)b * 49 * 256;
  #pragma unroll
  for (int mt = 0; mt < 2; ++mt) {
    int c0 = w * 32 + mt * 16 + lg * 4;
    float4 pb = *(const float4*)(proj_b + c0);
    #pragma unroll
    for (int qt = 0; qt < 4; ++qt) {
      int q = qt * 16 + lr;
      if (q < 49) {
        float4 ov;
        ov.x = po[mt][qt][0] + pb.x;
        ov.y = po[mt][qt][1] + pb.y;
        ov.z = po[mt][qt][2] + pb.z;
        ov.w = po[mt][qt][3] + pb.w;
        *(float4*)(od + q * 256 + c0) = ov;
      }
    }
  }
}

extern "C" void kernel_launch(void* const* d_in, const int* in_sizes, int n_in,
                              void* d_out, int out_size, void* d_ws, size_t ws_size,
                              hipStream_t stream) {
  const float* x      = (const float*)d_in[0];
  const float* qg     = (const float*)d_in[1];
  const float* qkv_w  = (const float*)d_in[2];
  const float* qkv_b  = (const float*)d_in[3];
  const float* proj_w = (const float*)d_in[4];
  const float* proj_b = (const float*)d_in[5];
  const float* table  = (const float*)d_in[6];
  float* out = (float*)d_out;

  char* ws = (char*)d_ws;                 // total scratch: ~2.62 MB
  short* wq_b  = (short*)ws;              // 262144 B  bf16 qkv_w [512][256]
  short* wp_b  = (short*)(ws + 262144);   // 131072 B  bf16 proj_w [256][256]
  short* q_b   = (short*)(ws + 393216);   // 2097152 B bf16 q padded [64][8][64][32]
  float* biasg = (float*)(ws + 2490368);  // 131072 B  f32 bias padded [8][64][64]

  const int prep_total = 131072 + 65536 + 1048576 + 32768;
  prep_kernel<<<(prep_total + 255) / 256, 256, 0, stream>>>(
      qkv_w, proj_w, qg, table, wq_b, wp_b, q_b, biasg);
  fused_win<<<4096, 512, 0, stream>>>(x, q_b, wq_b, wp_b, qkv_b, proj_b, biasg, out);
}

// Round 3
// 373.433 us; speedup vs baseline: 2.1573x; 2.1573x over previous
//
#include <hip/hip_runtime.h>

typedef __attribute__((ext_vector_type(4))) float f32x4;
typedef __attribute__((ext_vector_type(8))) short bf16x8;
typedef __attribute__((ext_vector_type(4))) short s16x4;

__device__ __forceinline__ short f2bf(float f) {
  union { float f; unsigned u; } x; x.f = f;
  return (short)((x.u + 0x7fffu + ((x.u >> 16) & 1u)) >> 16);   // RNE
}

__device__ __forceinline__ bf16x8 pack8(float4 a, float4 b) {
  bf16x8 v;
  v[0] = f2bf(a.x); v[1] = f2bf(a.y); v[2] = f2bf(a.z); v[3] = f2bf(a.w);
  v[4] = f2bf(b.x); v[5] = f2bf(b.y); v[6] = f2bf(b.z); v[7] = f2bf(b.w);
  return v;
}

// ---------------- prep: weights->bf16, q padded->bf16, bias [8][64][64] -----
__global__ __launch_bounds__(256) void prep_kernel(
    const float* __restrict__ qkv_w, const float* __restrict__ proj_w,
    const float* __restrict__ qg, const float* __restrict__ table,
    short* __restrict__ wq_b, short* __restrict__ wp_b,
    short* __restrict__ q_b, float* __restrict__ biasg)
{
  int idx = blockIdx.x * 256 + threadIdx.x;
  if (idx < 131072) { wq_b[idx] = f2bf(qkv_w[idx]); return; }
  idx -= 131072;
  if (idx < 65536) { wp_b[idx] = f2bf(proj_w[idx]); return; }
  idx -= 65536;
  if (idx < 1048576) {                       // q padded: [64 win][8 h][64 n][32 d]
    int d = idx & 31, n = (idx >> 5) & 63, hh = (idx >> 11) & 7, w = idx >> 14;
    float v = (n < 49) ? qg[((w * 8 + hh) * 49 + n) * 32 + d] : 0.f;
    q_b[idx] = f2bf(v);
    return;
  }
  idx -= 1048576;
  if (idx < 32768) {                         // bias padded: [8 h][64 q][64 k]
    int hh = idx >> 12, rem = idx & 4095;
    int q = rem >> 6, k = rem & 63;
    float v = 0.f;
    if (q < 49 && k < 49) {
      int di = q / 7 - k / 7 + 6, dj = q % 7 - k % 7 + 6;
      v = table[(di * 13 + dj) * 8 + hh];
    }
    biasg[idx] = v;
  }
}

// ---------------- fused per-window kernel -----------------------------------
// block = 1 window, 512 threads = 8 waves, wave w == head w. LDS = 80 KiB ->
// 2 blocks/CU. VGPR cap 128 (= 4 waves/SIMD = 2 blocks x 8 waves): NOT (512,4),
// which means 4 waves/EU -> 64 VGPR -> spills -> 9x HBM traffic (round-2 bug).
__global__ __launch_bounds__(512, 2) void fused_win(
    const float* __restrict__ x, const short* __restrict__ q_b,
    const short* __restrict__ wq_b, const short* __restrict__ wp_b,
    const float* __restrict__ qkv_b, const float* __restrict__ proj_b,
    const float* __restrict__ biasg, float* __restrict__ out)
{
  __shared__ __align__(16) char smem[81920];          // 80 KiB
  short* As = (short*)smem;                           // [64][128] x half-tile
  short* Kl = (short*)(smem + 16384);                 // [64 key][256 c] K
  short* vT = (short*)(smem + 49152);                 // [256 d][64 key] V^T
  short* Ol = (short*)(smem + 49152);                 // [64 q][256 c] (alias vT)

  const int tid = threadIdx.x;
  const int b   = blockIdx.x;
  const int lane = tid & 63;
  const int w   = tid >> 6;
  const int lr  = lane & 15;
  const int lg  = lane >> 4;
  short* Pw = (short*)(smem + 16384 + w * 4096);      // per-wave [64 q][32 k] (alias Kl)

  const float* xsrc = x + (long)b * 49 * 256;

  // -- phase 0: stage x half0 -> As; issue half1 loads (latency hides) ------
  float4 h1[2][2];
  int row0[2], s0[2];
  #pragma unroll
  for (int it = 0; it < 2; ++it) {
    int idx = it * 512 + tid;
    int row = idx >> 4, s = idx & 15;
    row0[it] = row; s0[it] = s;
    bf16x8 v = {};
    if (row < 49) {
      const float4* p = (const float4*)(xsrc + row * 256 + s * 8);
      v = pack8(p[0], p[1]);
    }
    *(bf16x8*)(&As[row * 128 + ((s ^ (row & 7)) << 3)]) = v;
  }
  #pragma unroll
  for (int it = 0; it < 2; ++it) {
    int row = row0[it], s = s0[it];
    if (row < 49) {
      const float4* p = (const float4*)(xsrc + row * 256 + 128 + s * 8);
      h1[it][0] = p[0]; h1[it][1] = p[1];
    } else {
      h1[it][0] = make_float4(0, 0, 0, 0); h1[it][1] = make_float4(0, 0, 0, 0);
    }
  }
  __syncthreads();                                    // B1

  // -- phase 1: kv = x @ qkv_w^T, K-split in halves --------------------------
  // waves 0-3: swapped -> acc[mt][nt] holds kv^T (rows=c, cols=key)
  // waves 4-7: normal  -> acc[mt][nt] holds kv   (rows=key, cols=c)
  f32x4 acc[4][4] = {};
  const short* wbase = wq_b + w * 64 * 256;
  #pragma unroll
  for (int kk = 0; kk < 4; ++kk) {
    bf16x8 xa[4], wf[4];
    #pragma unroll
    for (int t = 0; t < 4; ++t)
      xa[t] = *(const bf16x8*)(&As[(t * 16 + lr) * 128 + (((kk * 4 + lg) ^ (lr & 7)) << 3)]);
    #pragma unroll
    for (int t = 0; t < 4; ++t)
      wf[t] = *(const bf16x8*)(wbase + (t * 16 + lr) * 256 + kk * 32 + lg * 8);
    __builtin_amdgcn_s_setprio(1);
    if (w < 4) {
      #pragma unroll
      for (int mt = 0; mt < 4; ++mt)
        #pragma unroll
        for (int nt = 0; nt < 4; ++nt)
          acc[mt][nt] = __builtin_amdgcn_mfma_f32_16x16x32_bf16(wf[mt], xa[nt], acc[mt][nt], 0, 0, 0);
    } else {
      #pragma unroll
      for (int mt = 0; mt < 4; ++mt)
        #pragma unroll
        for (int nt = 0; nt < 4; ++nt)
          acc[mt][nt] = __builtin_amdgcn_mfma_f32_16x16x32_bf16(xa[mt], wf[nt], acc[mt][nt], 0, 0, 0);
    }
    __builtin_amdgcn_s_setprio(0);
  }
  __syncthreads();                                    // B2 (As reads done)
  #pragma unroll
  for (int it = 0; it < 2; ++it) {
    int row = row0[it], s = s0[it];
    *(bf16x8*)(&As[row * 128 + ((s ^ (row & 7)) << 3)]) = pack8(h1[it][0], h1[it][1]);
  }
  __syncthreads();                                    // B3
  #pragma unroll
  for (int kk = 0; kk < 4; ++kk) {
    bf16x8 xa[4], wf[4];
    #pragma unroll
    for (int t = 0; t < 4; ++t)
      xa[t] = *(const bf16x8*)(&As[(t * 16 + lr) * 128 + (((kk * 4 + lg) ^ (lr & 7)) << 3)]);
    #pragma unroll
    for (int t = 0; t < 4; ++t)
      wf[t] = *(const bf16x8*)(wbase + (t * 16 + lr) * 256 + 128 + kk * 32 + lg * 8);
    __builtin_amdgcn_s_setprio(1);
    if (w < 4) {
      #pragma unroll
      for (int mt = 0; mt < 4; ++mt)
        #pragma unroll
        for (int nt = 0; nt < 4; ++nt)
          acc[mt][nt] = __builtin_amdgcn_mfma_f32_16x16x32_bf16(wf[mt], xa[nt], acc[mt][nt], 0, 0, 0);
    } else {
      #pragma unroll
      for (int mt = 0; mt < 4; ++mt)
        #pragma unroll
        for (int nt = 0; nt < 4; ++nt)
          acc[mt][nt] = __builtin_amdgcn_mfma_f32_16x16x32_bf16(xa[mt], wf[nt], acc[mt][nt], 0, 0, 0);
    }
    __builtin_amdgcn_s_setprio(0);
  }

  // epilogue: +qkv_b, vectorized b64 LDS writes
  if (w < 4) {       // K: lane holds c = w*64+mt*16+lg*4+r, key = nt*16+lr
    #pragma unroll
    for (int mt = 0; mt < 4; ++mt) {
      int c0 = w * 64 + mt * 16 + lg * 4;
      float4 bv = *(const float4*)(qkv_b + c0);
      #pragma unroll
      for (int nt = 0; nt < 4; ++nt) {
        int key = nt * 16 + lr;
        s16x4 sv;
        sv[0] = f2bf(acc[mt][nt][0] + bv.x);
        sv[1] = f2bf(acc[mt][nt][1] + bv.y);
        sv[2] = f2bf(acc[mt][nt][2] + bv.z);
        sv[3] = f2bf(acc[mt][nt][3] + bv.w);
        *(s16x4*)(&Kl[key * 256 + ((((c0 >> 3) ^ (key & 7)) << 3)) + (c0 & 7)]) = sv;
      }
    }
  } else {           // V: lane holds key = mt*16+lg*4+r, d = (w-4)*64+nt*16+lr
    #pragma unroll
    for (int nt = 0; nt < 4; ++nt) {
      int d = (w - 4) * 64 + nt * 16 + lr;
      float bv = qkv_b[256 + d];
      #pragma unroll
      for (int mt = 0; mt < 4; ++mt) {
        int key0 = mt * 16 + lg * 4;
        s16x4 sv;
        sv[0] = f2bf(acc[mt][nt][0] + bv);
        sv[1] = f2bf(acc[mt][nt][1] + bv);
        sv[2] = f2bf(acc[mt][nt][2] + bv);
        sv[3] = f2bf(acc[mt][nt][3] + bv);
        *(s16x4*)(&vT[d * 64 + ((((key0 >> 3) ^ (d & 7)) << 3)) + (key0 & 7)]) = sv;
      }
    }
  }
  __syncthreads();                                    // B4

  // -- phase 2: S^T = mfma(K, Q): st[kt][qt] lane holds S[q=qt*16+lr][key=kt*16+lg*4+r]
  f32x4 st[4][4] = {};
  {
    const short* qsrc = q_b + ((long)(b >> 6) * 8 + w) * 2048;
    bf16x8 qa[4], kb[4];
    #pragma unroll
    for (int qt = 0; qt < 4; ++qt)
      qa[qt] = *(const bf16x8*)(qsrc + (qt * 16 + lr) * 32 + lg * 8);
    #pragma unroll
    for (int kt = 0; kt < 4; ++kt) {
      int key = kt * 16 + lr;
      kb[kt] = *(const bf16x8*)(&Kl[key * 256 + (((w * 4 + lg) ^ (key & 7)) << 3)]);
    }
    __builtin_amdgcn_s_setprio(1);
    #pragma unroll
    for (int kt = 0; kt < 4; ++kt)
      #pragma unroll
      for (int qt = 0; qt < 4; ++qt)
        st[kt][qt] = __builtin_amdgcn_mfma_f32_16x16x32_bf16(kb[kt], qa[qt], st[kt][qt], 0, 0, 0);
    __builtin_amdgcn_s_setprio(0);
  }
  __syncthreads();                                    // B5 (Kl dead -> P region)

  // -- phase 3: softmax rows are lane-local-ish (2 shfls per reduce) --------
  {
    const float* bh = biasg + w * 4096;
    const float sc = 0.17677669529663687f;            // 32^-0.5
    #pragma unroll
    for (int qt = 0; qt < 4; ++qt) {
      int q = qt * 16 + lr;
      float mx = -1e30f;
      #pragma unroll
      for (int kt = 0; kt < 4; ++kt) {
        int key0 = kt * 16 + lg * 4;
        float4 bv = *(const float4*)(bh + q * 64 + key0);
        #pragma unroll
        for (int r = 0; r < 4; ++r) {
          float t = st[kt][qt][r] * sc + ((r == 0) ? bv.x : (r == 1) ? bv.y : (r == 2) ? bv.z : bv.w);
          if (key0 + r >= 49) t = -1e30f;
          st[kt][qt][r] = t;
          mx = fmaxf(mx, t);
        }
      }
      mx = fmaxf(mx, __shfl_xor(mx, 16));
      mx = fmaxf(mx, __shfl_xor(mx, 32));
      float sum = 0.f;
      #pragma unroll
      for (int kt = 0; kt < 4; ++kt)
        #pragma unroll
        for (int r = 0; r < 4; ++r) {
          float e = __expf(st[kt][qt][r] - mx);
          st[kt][qt][r] = e; sum += e;
        }
      sum += __shfl_xor(sum, 16);
      sum += __shfl_xor(sum, 32);
      float rinv = 1.f / sum;                         // fold 1/sum into P
      #pragma unroll
      for (int kt = 0; kt < 4; ++kt)
        #pragma unroll
        for (int r = 0; r < 4; ++r) st[kt][qt][r] *= rinv;
    }
  }

  // -- phase 4: O^T = mfma(V^T, P^T), P chunked through per-wave LDS --------
  f32x4 o[2][4] = {};                                 // o[dt][qt]
  #pragma unroll
  for (int ks = 0; ks < 2; ++ks) {
    #pragma unroll
    for (int kh = 0; kh < 2; ++kh) {                  // write chunk keys [32ks,32ks+32)
      int kt = ks * 2 + kh;
      int kloc0 = kh * 16 + lg * 4;
      #pragma unroll
      for (int qt = 0; qt < 4; ++qt) {
        int q = qt * 16 + lr;
        s16x4 sv;
        sv[0] = f2bf(st[kt][qt][0]);
        sv[1] = f2bf(st[kt][qt][1]);
        sv[2] = f2bf(st[kt][qt][2]);
        sv[3] = f2bf(st[kt][qt][3]);
        *(s16x4*)(&Pw[q * 32 + ((((kloc0 >> 3) ^ ((q >> 1) & 3)) << 3)) + (kloc0 & 7)]) = sv;
      }
    }
    bf16x8 pa[4], vb[2];
    #pragma unroll
    for (int qt = 0; qt < 4; ++qt) {
      int q = qt * 16 + lr;
      pa[qt] = *(const bf16x8*)(&Pw[q * 32 + ((lg ^ ((q >> 1) & 3)) << 3)]);
    }
    #pragma unroll
    for (int dt = 0; dt < 2; ++dt) {
      int d = w * 32 + dt * 16 + lr;
      vb[dt] = *(const bf16x8*)(&vT[d * 64 + (((ks * 4 + lg) ^ (d & 7)) << 3)]);
    }
    __builtin_amdgcn_s_setprio(1);
    #pragma unroll
    for (int dt = 0; dt < 2; ++dt)
      #pragma unroll
      for (int qt = 0; qt < 4; ++qt)
        o[dt][qt] = __builtin_amdgcn_mfma_f32_16x16x32_bf16(vb[dt], pa[qt], o[dt][qt], 0, 0, 0);
    __builtin_amdgcn_s_setprio(0);
  }
  __syncthreads();                                    // B6 (vT dead)

  // -- phase 5: O^T -> Ol[q][c] with b64 writes -----------------------------
  #pragma unroll
  for (int dt = 0; dt < 2; ++dt) {
    int c0 = w * 32 + dt * 16 + lg * 4;
    #pragma unroll
    for (int qt = 0; qt < 4; ++qt) {
      int q = qt * 16 + lr;
      s16x4 sv;
      sv[0] = f2bf(o[dt][qt][0]);
      sv[1] = f2bf(o[dt][qt][1]);
      sv[2] = f2bf(o[dt][qt][2]);
      sv[3] = f2bf(o[dt][qt][3]);
      *(s16x4*)(&Ol[q * 256 + ((((c0 >> 3) ^ (q & 7)) << 3)) + (c0 & 7)]) = sv;
    }
  }
  __syncthreads();                                    // B7

  // -- phase 6: out = O @ proj_w^T + proj_b (swapped -> float4 stores) ------
  f32x4 po[2][4] = {};                                // po[mt][qt]: rows=out-col, cols=q
  const short* wpb = wp_b + w * 32 * 256;
  #pragma unroll
  for (int kk = 0; kk < 8; ++kk) {
    bf16x8 of[4], wf2[2];
    #pragma unroll
    for (int qt = 0; qt < 4; ++qt)
      of[qt] = *(const bf16x8*)(&Ol[(qt * 16 + lr) * 256 + (((kk * 4 + lg) ^ (lr & 7)) << 3)]);
    #pragma unroll
    for (int mt = 0; mt < 2; ++mt)
      wf2[mt] = *(const bf16x8*)(wpb + (mt * 16 + lr) * 256 + kk * 32 + lg * 8);
    __builtin_amdgcn_s_setprio(1);
    #pragma unroll
    for (int mt = 0; mt < 2; ++mt)
      #pragma unroll
      for (int qt = 0; qt < 4; ++qt)
        po[mt][qt] = __builtin_amdgcn_mfma_f32_16x16x32_bf16(wf2[mt], of[qt], po[mt][qt], 0, 0, 0);
    __builtin_amdgcn_s_setprio(0);
  }
  float* od = out + (long)b * 49 * 256;
  #pragma unroll
  for (int mt = 0; mt < 2; ++mt) {
    int c0 = w * 32 + mt * 16 + lg * 4;
    float4 pb = *(const float4*)(proj_b + c0);
    #pragma unroll
    for (int qt = 0; qt < 4; ++qt) {
      int q = qt * 16 + lr;
      if (q < 49) {
        float4 ov;
        ov.x = po[mt][qt][0] + pb.x;
        ov.y = po[mt][qt][1] + pb.y;
        ov.z = po[mt][qt][2] + pb.z;
        ov.w = po[mt][qt][3] + pb.w;
        *(float4*)(od + q * 256 + c0) = ov;
      }
    }
  }
}

extern "C" void kernel_launch(void* const* d_in, const int* in_sizes, int n_in,
                              void* d_out, int out_size, void* d_ws, size_t ws_size,
                              hipStream_t stream) {
  const float* x      = (const float*)d_in[0];
  const float* qg     = (const float*)d_in[1];
  const float* qkv_w  = (const float*)d_in[2];
  const float* qkv_b  = (const float*)d_in[3];
  const float* proj_w = (const float*)d_in[4];
  const float* proj_b = (const float*)d_in[5];
  const float* table  = (const float*)d_in[6];
  float* out = (float*)d_out;

  char* ws = (char*)d_ws;                 // total scratch: ~2.62 MB
  short* wq_b  = (short*)ws;              // 262144 B  bf16 qkv_w [512][256]
  short* wp_b  = (short*)(ws + 262144);   // 131072 B  bf16 proj_w [256][256]
  short* q_b   = (short*)(ws + 393216);   // 2097152 B bf16 q padded [64][8][64][32]
  float* biasg = (float*)(ws + 2490368);  // 131072 B  f32 bias padded [8][64][64]

  const int prep_total = 131072 + 65536 + 1048576 + 32768;
  prep_kernel<<<(prep_total + 255) / 256, 256, 0, stream>>>(
      qkv_w, proj_w, qg, table, wq_b, wp_b, q_b, biasg);
  fused_win<<<4096, 512, 0, stream>>>(x, q_b, wq_b, wp_b, qkv_b, proj_b, biasg, out);
}

// Round 4
// 355.654 us; speedup vs baseline: 2.2652x; 1.0500x over previous
//
#include <hip/hip_runtime.h>

typedef __attribute__((ext_vector_type(4))) float f32x4;
typedef __attribute__((ext_vector_type(8))) short bf16x8;
typedef __attribute__((ext_vector_type(4))) short s16x4;

__device__ __forceinline__ short f2bf(float f) {
  union { float f; unsigned u; } x; x.f = f;
  return (short)((x.u + 0x7fffu + ((x.u >> 16) & 1u)) >> 16);   // RNE
}

__device__ __forceinline__ bf16x8 pack8(float4 a, float4 b) {
  bf16x8 v;
  v[0] = f2bf(a.x); v[1] = f2bf(a.y); v[2] = f2bf(a.z); v[3] = f2bf(a.w);
  v[4] = f2bf(b.x); v[5] = f2bf(b.y); v[6] = f2bf(b.z); v[7] = f2bf(b.w);
  return v;
}

// ---------------- prep: weights->bf16, q padded->bf16, bias [8][64][64] -----
__global__ __launch_bounds__(256) void prep_kernel(
    const float* __restrict__ qkv_w, const float* __restrict__ proj_w,
    const float* __restrict__ qg, const float* __restrict__ table,
    short* __restrict__ wq_b, short* __restrict__ wp_b,
    short* __restrict__ q_b, float* __restrict__ biasg)
{
  int idx = blockIdx.x * 256 + threadIdx.x;
  if (idx < 131072) { wq_b[idx] = f2bf(qkv_w[idx]); return; }
  idx -= 131072;
  if (idx < 65536) { wp_b[idx] = f2bf(proj_w[idx]); return; }
  idx -= 65536;
  if (idx < 1048576) {                       // q padded: [64 win][8 h][64 n][32 d]
    int d = idx & 31, n = (idx >> 5) & 63, hh = (idx >> 11) & 7, w = idx >> 14;
    float v = (n < 49) ? qg[((w * 8 + hh) * 49 + n) * 32 + d] : 0.f;
    q_b[idx] = f2bf(v);
    return;
  }
  idx -= 1048576;
  if (idx < 32768) {                         // bias padded: [8 h][64 q][64 k]
    int hh = idx >> 12, rem = idx & 4095;
    int q = rem >> 6, k = rem & 63;
    float v = 0.f;
    if (q < 49 && k < 49) {
      int di = q / 7 - k / 7 + 6, dj = q % 7 - k % 7 + 6;
      v = table[(di * 13 + dj) * 8 + hh];
    }
    biasg[idx] = v;
  }
}

// ---------------- fused per-window kernel -----------------------------------
// block = 1 window, 1024 threads = 16 waves. Per-wave tiles HALVED vs the
// 512-thread version so VGPR+AGPR total stays <=128 (4 waves/SIMD, 50% occ):
//  - kv GEMM: wave w<8 computes K cols [32w,32w+32) swapped; w>=8 V d-chunk.
//  - attention: 2 waves per head; wave handles q-rows [qh*32, qh*32+32).
//  - proj: wave w computes out-cols [16w, 16w+16) swapped.
// NOTE (round-3 lesson): rocprof VGPR_Count excludes AGPRs; occupancy is set
// by the UNIFIED total. 64-reg accumulators made round-3 168 total -> 1 blk/CU.
__global__ __launch_bounds__(1024, 4) void fused_win(
    const float* __restrict__ x, const short* __restrict__ q_b,
    const short* __restrict__ wq_b, const short* __restrict__ wp_b,
    const float* __restrict__ qkv_b, const float* __restrict__ proj_b,
    const float* __restrict__ biasg, float* __restrict__ out)
{
  __shared__ __align__(16) char smem[81920];          // 80 KiB
  short* As = (short*)smem;                           // [64][128] x half-tile
  short* Kl = (short*)(smem + 16384);                 // [64 key][256 c] K
  short* vT = (short*)(smem + 49152);                 // [256 d][64 key] V^T
  short* Ol = (short*)(smem + 49152);                 // [64 q][256 c] (alias vT)

  const int tid = threadIdx.x;
  const int b   = blockIdx.x;
  const int lane = tid & 63;
  const int w   = tid >> 6;        // 0..15
  const int lr  = lane & 15;
  const int lg  = lane >> 4;

  const float* xsrc = x + (long)b * 49 * 256;

  // -- phase 0: stage x half0 -> As (1 slot/thread); prefetch half1 to regs --
  const int xrow = tid >> 4, xs = tid & 15;
  {
    bf16x8 v = {};
    if (xrow < 49) {
      const float4* p = (const float4*)(xsrc + xrow * 256 + xs * 8);
      v = pack8(p[0], p[1]);
    }
    *(bf16x8*)(&As[xrow * 128 + ((xs ^ (xrow & 7)) << 3)]) = v;
  }
  float4 h1a = make_float4(0, 0, 0, 0), h1b = make_float4(0, 0, 0, 0);
  if (xrow < 49) {
    const float4* p = (const float4*)(xsrc + xrow * 256 + 128 + xs * 8);
    h1a = p[0]; h1b = p[1];
  }
  __syncthreads();                                    // B1

  // -- phase 1: kv = x @ qkv_w^T -------------------------------------------
  // waves 0-7 (K): swapped -> acc[mt*4+nt] = kv^T chunk, rows=c(32), cols=key(64)
  // waves 8-15 (V): normal -> acc[mt*2+nt] = kv chunk, rows=key(64), cols=d(32)
  const bool isK = (w < 8);
  f32x4 acc[8] = {};
  const short* wbase = wq_b + (isK ? (w * 32) : (256 + (w - 8) * 32)) * 256;

  #pragma unroll
  for (int kk = 0; kk < 4; ++kk) {                    // K-half 0
    bf16x8 xa[4], wf[2];
    #pragma unroll
    for (int t = 0; t < 4; ++t)
      xa[t] = *(const bf16x8*)(&As[(t * 16 + lr) * 128 + (((kk * 4 + lg) ^ (lr & 7)) << 3)]);
    #pragma unroll
    for (int t = 0; t < 2; ++t)
      wf[t] = *(const bf16x8*)(wbase + (t * 16 + lr) * 256 + kk * 32 + lg * 8);
    __builtin_amdgcn_s_setprio(1);
    if (isK) {
      #pragma unroll
      for (int mt = 0; mt < 2; ++mt)
        #pragma unroll
        for (int nt = 0; nt < 4; ++nt)
          acc[mt * 4 + nt] = __builtin_amdgcn_mfma_f32_16x16x32_bf16(wf[mt], xa[nt], acc[mt * 4 + nt], 0, 0, 0);
    } else {
      #pragma unroll
      for (int mt = 0; mt < 4; ++mt)
        #pragma unroll
        for (int nt = 0; nt < 2; ++nt)
          acc[mt * 2 + nt] = __builtin_amdgcn_mfma_f32_16x16x32_bf16(xa[mt], wf[nt], acc[mt * 2 + nt], 0, 0, 0);
    }
    __builtin_amdgcn_s_setprio(0);
  }
  __syncthreads();                                    // B2 (As half0 reads done)
  *(bf16x8*)(&As[xrow * 128 + ((xs ^ (xrow & 7)) << 3)]) = pack8(h1a, h1b);
  __syncthreads();                                    // B3
  #pragma unroll
  for (int kk = 0; kk < 4; ++kk) {                    // K-half 1
    bf16x8 xa[4], wf[2];
    #pragma unroll
    for (int t = 0; t < 4; ++t)
      xa[t] = *(const bf16x8*)(&As[(t * 16 + lr) * 128 + (((kk * 4 + lg) ^ (lr & 7)) << 3)]);
    #pragma unroll
    for (int t = 0; t < 2; ++t)
      wf[t] = *(const bf16x8*)(wbase + (t * 16 + lr) * 256 + 128 + kk * 32 + lg * 8);
    __builtin_amdgcn_s_setprio(1);
    if (isK) {
      #pragma unroll
      for (int mt = 0; mt < 2; ++mt)
        #pragma unroll
        for (int nt = 0; nt < 4; ++nt)
          acc[mt * 4 + nt] = __builtin_amdgcn_mfma_f32_16x16x32_bf16(wf[mt], xa[nt], acc[mt * 4 + nt], 0, 0, 0);
    } else {
      #pragma unroll
      for (int mt = 0; mt < 4; ++mt)
        #pragma unroll
        for (int nt = 0; nt < 2; ++nt)
          acc[mt * 2 + nt] = __builtin_amdgcn_mfma_f32_16x16x32_bf16(xa[mt], wf[nt], acc[mt * 2 + nt], 0, 0, 0);
    }
    __builtin_amdgcn_s_setprio(0);
  }

  // epilogue: +qkv_b, b64 LDS writes
  if (isK) {         // lane holds c = w*32+mt*16+lg*4+r, key = nt*16+lr
    #pragma unroll
    for (int mt = 0; mt < 2; ++mt) {
      int c0 = w * 32 + mt * 16 + lg * 4;
      float4 bv = *(const float4*)(qkv_b + c0);
      #pragma unroll
      for (int nt = 0; nt < 4; ++nt) {
        int key = nt * 16 + lr;
        s16x4 sv;
        sv[0] = f2bf(acc[mt * 4 + nt][0] + bv.x);
        sv[1] = f2bf(acc[mt * 4 + nt][1] + bv.y);
        sv[2] = f2bf(acc[mt * 4 + nt][2] + bv.z);
        sv[3] = f2bf(acc[mt * 4 + nt][3] + bv.w);
        *(s16x4*)(&Kl[key * 256 + ((((c0 >> 3) ^ (key & 7)) << 3)) + (c0 & 7)]) = sv;
      }
    }
  } else {           // lane holds key = mt*16+lg*4+r, d = (w-8)*32+nt*16+lr
    #pragma unroll
    for (int nt = 0; nt < 2; ++nt) {
      int d = (w - 8) * 32 + nt * 16 + lr;
      float bv = qkv_b[256 + d];
      #pragma unroll
      for (int mt = 0; mt < 4; ++mt) {
        int key0 = mt * 16 + lg * 4;
        s16x4 sv;
        sv[0] = f2bf(acc[mt * 2 + nt][0] + bv);
        sv[1] = f2bf(acc[mt * 2 + nt][1] + bv);
        sv[2] = f2bf(acc[mt * 2 + nt][2] + bv);
        sv[3] = f2bf(acc[mt * 2 + nt][3] + bv);
        *(s16x4*)(&vT[d * 64 + ((((key0 >> 3) ^ (d & 7)) << 3)) + (key0 & 7)]) = sv;
      }
    }
  }
  __syncthreads();                                    // B4

  // -- phase 2: S^T = mfma(K, Q); wave = (head h, q-half qh) ----------------
  const int h = w >> 1, qh = w & 1;
  f32x4 st[4][2] = {};                                // st[kt][qt]
  {
    const short* qsrc = q_b + ((long)(b >> 6) * 8 + h) * 2048 + qh * 1024;
    bf16x8 qa[2], kb[4];
    #pragma unroll
    for (int qt = 0; qt < 2; ++qt)
      qa[qt] = *(const bf16x8*)(qsrc + (qt * 16 + lr) * 32 + lg * 8);
    #pragma unroll
    for (int kt = 0; kt < 4; ++kt) {
      int key = kt * 16 + lr;
      kb[kt] = *(const bf16x8*)(&Kl[key * 256 + (((h * 4 + lg) ^ (key & 7)) << 3)]);
    }
    __builtin_amdgcn_s_setprio(1);
    #pragma unroll
    for (int kt = 0; kt < 4; ++kt)
      #pragma unroll
      for (int qt = 0; qt < 2; ++qt)
        st[kt][qt] = __builtin_amdgcn_mfma_f32_16x16x32_bf16(kb[kt], qa[qt], st[kt][qt], 0, 0, 0);
    __builtin_amdgcn_s_setprio(0);
  }
  __syncthreads();                                    // B5 (Kl dead -> P region)

  // -- phase 3: softmax; row q = qh*32+qt*16+lr, keys in-lane (2 shfls) -----
  {
    const float* bh = biasg + h * 4096;
    const float sc = 0.17677669529663687f;            // 32^-0.5
    #pragma unroll
    for (int qt = 0; qt < 2; ++qt) {
      int q = qh * 32 + qt * 16 + lr;
      float mx = -1e30f;
      #pragma unroll
      for (int kt = 0; kt < 4; ++kt) {
        int key0 = kt * 16 + lg * 4;
        float4 bv = *(const float4*)(bh + q * 64 + key0);
        #pragma unroll
        for (int r = 0; r < 4; ++r) {
          float t = st[kt][qt][r] * sc + ((r == 0) ? bv.x : (r == 1) ? bv.y : (r == 2) ? bv.z : bv.w);
          if (key0 + r >= 49) t = -1e30f;
          st[kt][qt][r] = t;
          mx = fmaxf(mx, t);
        }
      }
      mx = fmaxf(mx, __shfl_xor(mx, 16));
      mx = fmaxf(mx, __shfl_xor(mx, 32));
      float sum = 0.f;
      #pragma unroll
      for (int kt = 0; kt < 4; ++kt)
        #pragma unroll
        for (int r = 0; r < 4; ++r) {
          float e = __expf(st[kt][qt][r] - mx);
          st[kt][qt][r] = e; sum += e;
        }
      sum += __shfl_xor(sum, 16);
      sum += __shfl_xor(sum, 32);
      float rinv = 1.f / sum;                         // fold 1/sum into P
      #pragma unroll
      for (int kt = 0; kt < 4; ++kt)
        #pragma unroll
        for (int r = 0; r < 4; ++r) st[kt][qt][r] *= rinv;
    }
  }

  // -- phase 4: O^T = mfma(V^T, P^T); P chunks via private per-wave LDS -----
  short* Pw = (short*)(smem + 16384 + w * 2048);      // [32 q][32 k] (alias Kl)
  f32x4 o[2][2] = {};                                 // o[dt][qt]
  #pragma unroll
  for (int ks = 0; ks < 2; ++ks) {
    #pragma unroll
    for (int kh = 0; kh < 2; ++kh) {
      int kt = ks * 2 + kh;
      int kloc0 = kh * 16 + lg * 4;
      #pragma unroll
      for (int qt = 0; qt < 2; ++qt) {
        int qloc = qt * 16 + lr;
        s16x4 sv;
        sv[0] = f2bf(st[kt][qt][0]);
        sv[1] = f2bf(st[kt][qt][1]);
        sv[2] = f2bf(st[kt][qt][2]);
        sv[3] = f2bf(st[kt][qt][3]);
        *(s16x4*)(&Pw[qloc * 32 + ((((kloc0 >> 3) ^ ((qloc >> 1) & 3)) << 3)) + (kloc0 & 7)]) = sv;
      }
    }
    bf16x8 pa[2], vb[2];
    #pragma unroll
    for (int qt = 0; qt < 2; ++qt) {
      int qloc = qt * 16 + lr;
      pa[qt] = *(const bf16x8*)(&Pw[qloc * 32 + ((lg ^ ((qloc >> 1) & 3)) << 3)]);
    }
    #pragma unroll
    for (int dt = 0; dt < 2; ++dt) {
      int d = h * 32 + dt * 16 + lr;
      vb[dt] = *(const bf16x8*)(&vT[d * 64 + (((ks * 4 + lg) ^ (d & 7)) << 3)]);
    }
    __builtin_amdgcn_s_setprio(1);
    #pragma unroll
    for (int dt = 0; dt < 2; ++dt)
      #pragma unroll
      for (int qt = 0; qt < 2; ++qt)
        o[dt][qt] = __builtin_amdgcn_mfma_f32_16x16x32_bf16(vb[dt], pa[qt], o[dt][qt], 0, 0, 0);
    __builtin_amdgcn_s_setprio(0);
  }
  __syncthreads();                                    // B6 (vT dead)

  // -- phase 5: O^T -> Ol[q][c], b64 writes ---------------------------------
  #pragma unroll
  for (int dt = 0; dt < 2; ++dt) {
    int c0 = h * 32 + dt * 16 + lg * 4;
    #pragma unroll
    for (int qt = 0; qt < 2; ++qt) {
      int q = qh * 32 + qt * 16 + lr;
      s16x4 sv;
      sv[0] = f2bf(o[dt][qt][0]);
      sv[1] = f2bf(o[dt][qt][1]);
      sv[2] = f2bf(o[dt][qt][2]);
      sv[3] = f2bf(o[dt][qt][3]);
      *(s16x4*)(&Ol[q * 256 + ((((c0 >> 3) ^ (q & 7)) << 3)) + (c0 & 7)]) = sv;
    }
  }
  __syncthreads();                                    // B7

  // -- phase 6: out = O @ proj_w^T + proj_b (swapped -> float4 stores) ------
  f32x4 po[4] = {};                                   // po[qt]: rows=out-c(16), cols=q
  const short* wpb = wp_b + (w * 16) * 256;
  #pragma unroll
  for (int kk = 0; kk < 8; ++kk) {
    bf16x8 of[4], wf2;
    #pragma unroll
    for (int qt = 0; qt < 4; ++qt)
      of[qt] = *(const bf16x8*)(&Ol[(qt * 16 + lr) * 256 + (((kk * 4 + lg) ^ (lr & 7)) << 3)]);
    wf2 = *(const bf16x8*)(wpb + lr * 256 + kk * 32 + lg * 8);
    __builtin_amdgcn_s_setprio(1);
    #pragma unroll
    for (int qt = 0; qt < 4; ++qt)
      po[qt] = __builtin_amdgcn_mfma_f32_16x16x32_bf16(wf2, of[qt], po[qt], 0, 0, 0);
    __builtin_amdgcn_s_setprio(0);
  }
  float* od = out + (long)b * 49 * 256;
  {
    int c0 = w * 16 + lg * 4;
    float4 pb = *(const float4*)(proj_b + c0);
    #pragma unroll
    for (int qt = 0; qt < 4; ++qt) {
      int q = qt * 16 + lr;
      if (q < 49) {
        float4 ov;
        ov.x = po[qt][0] + pb.x;
        ov.y = po[qt][1] + pb.y;
        ov.z = po[qt][2] + pb.z;
        ov.w = po[qt][3] + pb.w;
        *(float4*)(od + q * 256 + c0) = ov;
      }
    }
  }
}

extern "C" void kernel_launch(void* const* d_in, const int* in_sizes, int n_in,
                              void* d_out, int out_size, void* d_ws, size_t ws_size,
                              hipStream_t stream) {
  const float* x      = (const float*)d_in[0];
  const float* qg     = (const float*)d_in[1];
  const float* qkv_w  = (const float*)d_in[2];
  const float* qkv_b  = (const float*)d_in[3];
  const float* proj_w = (const float*)d_in[4];
  const float* proj_b = (const float*)d_in[5];
  const float* table  = (const float*)d_in[6];
  float* out = (float*)d_out;

  char* ws = (char*)d_ws;                 // total scratch: ~2.62 MB
  short* wq_b  = (short*)ws;              // 262144 B  bf16 qkv_w [512][256]
  short* wp_b  = (short*)(ws + 262144);   // 131072 B  bf16 proj_w [256][256]
  short* q_b   = (short*)(ws + 393216);   // 2097152 B bf16 q padded [64][8][64][32]
  float* biasg = (float*)(ws + 2490368);  // 131072 B  f32 bias padded [8][64][64]

  const int prep_total = 131072 + 65536 + 1048576 + 32768;
  prep_kernel<<<(prep_total + 255) / 256, 256, 0, stream>>>(
      qkv_w, proj_w, qg, table, wq_b, wp_b, q_b, biasg);
  fused_win<<<4096, 1024, 0, stream>>>(x, q_b, wq_b, wp_b, qkv_b, proj_b, biasg, out);
}